// Round 1
// baseline (1357.265 us; speedup 1.0000x reference)
//
#include <hip/hip_runtime.h>
#include <math.h>

typedef float vfloat4 __attribute__((ext_vector_type(4)));

#define NBLK 1024u

__device__ __forceinline__ float dot4(vfloat4 a, vfloat4 b) {
    return a.x * b.x + a.y * b.y + a.z * b.z + a.w * b.w;
}

__device__ __forceinline__ void reduce2(float& a, float& b) {
#pragma unroll
    for (int off = 32; off; off >>= 1) {
        a += __shfl_down(a, off, 64);
        b += __shfl_down(b, off, 64);
    }
}

// Device-scope grid barrier. Monotonic counter in ws (zeroed by hipMemsetAsync
// at launch). All 1024 blocks are co-resident by construction:
// __launch_bounds__(256,4) caps VGPR at 128 -> 4 blocks/CU x 256 CU = 1024.
// Bounded spin: on any residency surprise we break (verification fails loudly)
// instead of hanging the queue.
__device__ __forceinline__ void gridbar(unsigned* cnt, unsigned target) {
    __syncthreads();                       // drains vmcnt: block stores complete at L2
    if (threadIdx.x == 0) {
        __threadfence();                   // agent release: wbl2 -> stores visible cross-XCD
        __hip_atomic_fetch_add(cnt, 1u, __ATOMIC_RELEASE, __HIP_MEMORY_SCOPE_AGENT);
        unsigned guard = 0;
        while (__hip_atomic_load(cnt, __ATOMIC_ACQUIRE, __HIP_MEMORY_SCOPE_AGENT) < target) {
            __builtin_amdgcn_s_sleep(2);
            if (++guard > 30000000u) break;  // failsafe
        }
        __threadfence();                   // agent acquire: inv stale L1/L2 lines
    }
    __syncthreads();
}

// ---------------------------------------------------------------------------
// One persistent kernel, 1024 blocks x 256 threads (4 waves/block).
// P1a: enc0 (4096x16384)  - wave owns a 1024-col chunk (v/t in regs), 16 rows
// P1b: enc0 epilogue      - 4-partial reduce + sigmoid
// P2 : enc1 (1024x4096)   - block-per-row, 4-wave col split
// P3 : head (block 0)     - z/dz, sindy library, dzb, dec0
// P4 : dec1 (4096x1024)   - wave-per-row
// P5 : dec2 (16384x4096)  - wave owns a 1024-col chunk (v/t in regs), 16 rows,
//                           in-block combine + identity epilogue
// ---------------------------------------------------------------------------
__global__ __launch_bounds__(256, 4) void sindy_fused(
    const float* __restrict__ x, const float* __restrict__ dx,
    const float* __restrict__ we_w0, const float* __restrict__ we_b0,
    const float* __restrict__ we_w1, const float* __restrict__ we_b1,
    const float* __restrict__ we_w2, const float* __restrict__ we_b2,
    const float* __restrict__ wd_w0, const float* __restrict__ wd_b0,
    const float* __restrict__ wd_w1, const float* __restrict__ wd_b1,
    const float* __restrict__ wd_w2, const float* __restrict__ wd_b2,
    const float* __restrict__ Ew, const float* __restrict__ Eb,
    float* __restrict__ h1, float* __restrict__ t1,
    float* __restrict__ h2, float* __restrict__ t2,
    float* __restrict__ g1, float* __restrict__ s1,
    float* __restrict__ g2, float* __restrict__ s2,
    float* __restrict__ part1, unsigned* __restrict__ bar,
    float* __restrict__ out, float* __restrict__ xb, float* __restrict__ dxb)
{
    __shared__ float red[4][16][2];
    __shared__ __align__(16) float theta[984];
    __shared__ float z_s[16], dz_s[16], dzb_s[16];

    const int tid  = (int)threadIdx.x;
    const int lane = tid & 63;
    const int w    = tid >> 6;          // wave 0..3
    const int b    = (int)blockIdx.x;   // 0..1023

    // ================= P1a: encoder L0 partial GEMV =================
    // group g = b>>2 owns rows 16g..16g+15; block-in-group jb = b&3;
    // wave chunk c = 4*jb + w owns cols [1024c, 1024c+1024).
    {
        const int g  = b >> 2;
        const int jb = b & 3;
        const int c  = (jb << 2) + w;
        const int r0 = g << 4;
        const vfloat4* x4 = (const vfloat4*)x;
        const vfloat4* d4 = (const vfloat4*)dx;
        vfloat4 vv[4], tt[4];
#pragma unroll
        for (int k = 0; k < 4; ++k) {
            const int i = c * 256 + k * 64 + lane;
            vv[k] = x4[i];
            tt[k] = d4[i];
        }
        const vfloat4* W4 = (const vfloat4*)we_w0;
#pragma unroll 2
        for (int r = 0; r < 16; ++r) {
            const vfloat4* Wr = W4 + (size_t)(r0 + r) * 4096 + (size_t)c * 256;
            float ah = 0.f, at = 0.f;
#pragma unroll
            for (int k = 0; k < 4; ++k) {
                vfloat4 wv = __builtin_nontemporal_load(&Wr[k * 64 + lane]);
                ah += dot4(wv, vv[k]);
                at += dot4(wv, tt[k]);
            }
            reduce2(ah, at);
            if (lane == 0) { red[w][r][0] = ah; red[w][r][1] = at; }
        }
        __syncthreads();
        if (tid < 32) {
            const int r = tid >> 1, s = tid & 1;
            float sum = red[0][r][s] + red[1][r][s] + red[2][r][s] + red[3][r][s];
            part1[((size_t)(r0 + r) * 2 + s) * 4 + jb] = sum;  // [row][stream][jb]
        }
    }
    gridbar(bar, 1u * NBLK);

    // ================= P1b: enc0 reduce + sigmoid epilogue =================
    {
        const int gt = b * 256 + tid;
        if (gt < 4096) {
            const vfloat4* p4 = (const vfloat4*)part1;
            vfloat4 ph = p4[gt * 2];
            vfloat4 pt = p4[gt * 2 + 1];
            float ah = ph.x + ph.y + ph.z + ph.w + we_b0[gt];
            float at = pt.x + pt.y + pt.z + pt.w;
            float sg = 1.f / (1.f + expf(-ah));
            h1[gt] = sg;
            t1[gt] = sg * (1.f - sg) * at;
        }
    }
    gridbar(bar, 2u * NBLK);

    // ================= P2: encoder L1 (block b = row b) =================
    {
        const vfloat4* W4 = (const vfloat4*)we_w1 + (size_t)b * 1024;
        const vfloat4* v4 = (const vfloat4*)h1;
        const vfloat4* t4 = (const vfloat4*)t1;
        float ah = 0.f, at = 0.f;
#pragma unroll
        for (int k = 0; k < 4; ++k) {
            const int i = w * 256 + k * 64 + lane;
            vfloat4 wv = __builtin_nontemporal_load(&W4[i]);
            ah += dot4(wv, v4[i]);
            at += dot4(wv, t4[i]);
        }
        reduce2(ah, at);
        if (lane == 0) { red[w][0][0] = ah; red[w][0][1] = at; }
        __syncthreads();
        if (tid == 0) {
            float A = red[0][0][0] + red[1][0][0] + red[2][0][0] + red[3][0][0] + we_b1[b];
            float T = red[0][0][1] + red[1][0][1] + red[2][0][1] + red[3][0][1];
            float sg = 1.f / (1.f + expf(-A));
            h2[b] = sg;
            t2[b] = sg * (1.f - sg) * T;
        }
    }
    gridbar(bar, 3u * NBLK);

    // ================= P3: head (block 0 only) =================
    if (b == 0) {
        // ---- z, dz: wave w handles rows {w, 4+w, 8+w, 12+w} ----
        const vfloat4* h4 = (const vfloat4*)h2;
        const vfloat4* t4 = (const vfloat4*)t2;
#pragma unroll
        for (int rr = 0; rr < 4; ++rr) {
            const int row = (rr << 2) + w;
            const vfloat4* Wr = (const vfloat4*)we_w2 + (size_t)row * 256;
            float ah = 0.f, at = 0.f;
#pragma unroll
            for (int k = 0; k < 4; ++k) {
                const int i = k * 64 + lane;
                vfloat4 wv = Wr[i];
                ah += dot4(wv, h4[i]);
                at += dot4(wv, t4[i]);
            }
            reduce2(ah, at);
            if (lane == 0) { z_s[row] = ah + we_b2[row]; dz_s[row] = at; }
        }
        __syncthreads();

        // ---- sindy library: [1]*16 ++ z ++ quad(136) ++ cub(816) ----
        if (tid < 16) { theta[tid] = 1.0f; theta[16 + tid] = z_s[tid]; }
        for (int t5 = tid; t5 < 136; t5 += 256) {
            int rem = t5, i = 0;
            while (rem >= 16 - i) { rem -= 16 - i; i++; }
            theta[32 + t5] = z_s[i] * z_s[i + rem];
        }
        for (int t5 = tid; t5 < 816; t5 += 256) {
            int rem = t5, i = 0;
            for (;;) { int cnt = (16 - i) * (17 - i) >> 1; if (rem < cnt) break; rem -= cnt; i++; }
            int j = i;
            while (rem >= 16 - j) { rem -= 16 - j; j++; }
            theta[168 + t5] = z_s[i] * z_s[j] * z_s[j + rem];
        }
        __syncthreads();

        // ---- dzb = E_w @ theta + E_b ----
        const vfloat4* th4 = (const vfloat4*)theta;
#pragma unroll
        for (int rr = 0; rr < 4; ++rr) {
            const int row = (rr << 2) + w;
            const vfloat4* Er = (const vfloat4*)Ew + (size_t)row * 246;
            float a = 0.f;
#pragma unroll
            for (int k = 0; k < 4; ++k) {
                const int i = k * 64 + lane;
                if (i < 246) a += dot4(Er[i], th4[i]);
            }
#pragma unroll
            for (int off = 32; off; off >>= 1) a += __shfl_down(a, off, 64);
            if (lane == 0) dzb_s[row] = a + Eb[row];
        }
        __syncthreads();

        if (tid < 16) {
            out[tid]      = z_s[tid];
            out[16 + tid] = dz_s[tid];
            out[32 + tid] = dzb_s[tid];
        }

        // ---- decoder layer 0: 1024 rows, 4 rows/thread ----
#pragma unroll
        for (int q = 0; q < 4; ++q) {
            const int row = tid + (q << 8);
            const vfloat4* U4 = (const vfloat4*)wd_w0 + (size_t)row * 4;
            float ah = 0.f, at = 0.f;
#pragma unroll
            for (int p = 0; p < 4; ++p) {
                vfloat4 u = U4[p];
                ah += u.x * z_s[4*p] + u.y * z_s[4*p+1] + u.z * z_s[4*p+2] + u.w * z_s[4*p+3];
                at += u.x * dzb_s[4*p] + u.y * dzb_s[4*p+1] + u.z * dzb_s[4*p+2] + u.w * dzb_s[4*p+3];
            }
            ah += wd_b0[row];
            float sg = 1.f / (1.f + expf(-ah));
            g1[row] = sg;
            s1[row] = sg * (1.f - sg) * at;
        }
    }
    gridbar(bar, 4u * NBLK);

    // ================= P4: decoder L1 (wave-per-row) =================
    {
        const int row = (b << 2) + w;   // 0..4095
        const vfloat4* Wr = (const vfloat4*)wd_w1 + (size_t)row * 256;
        const vfloat4* v4 = (const vfloat4*)g1;
        const vfloat4* t4 = (const vfloat4*)s1;
        float ah = 0.f, at = 0.f;
#pragma unroll
        for (int k = 0; k < 4; ++k) {
            const int i = k * 64 + lane;
            vfloat4 wv = __builtin_nontemporal_load(&Wr[i]);
            ah += dot4(wv, v4[i]);
            at += dot4(wv, t4[i]);
        }
        reduce2(ah, at);
        if (lane == 0) {
            ah += wd_b1[row];
            float sg = 1.f / (1.f + expf(-ah));
            g2[row] = sg;
            s2[row] = sg * (1.f - sg) * at;
        }
    }
    gridbar(bar, 5u * NBLK);

    // ================= P5: decoder L2 (16384x4096), in-block =================
    // block b owns rows 16b..16b+15; wave w owns cols [1024w, 1024w+1024).
    {
        const vfloat4* g4 = (const vfloat4*)g2;
        const vfloat4* s4 = (const vfloat4*)s2;
        vfloat4 vv[4], tt[4];
#pragma unroll
        for (int k = 0; k < 4; ++k) {
            const int i = w * 256 + k * 64 + lane;
            vv[k] = g4[i];
            tt[k] = s4[i];
        }
        const int r0 = b << 4;
        const vfloat4* W4 = (const vfloat4*)wd_w2;
#pragma unroll 2
        for (int r = 0; r < 16; ++r) {
            const vfloat4* Wr = W4 + (size_t)(r0 + r) * 1024 + (size_t)w * 256;
            float ah = 0.f, at = 0.f;
#pragma unroll
            for (int k = 0; k < 4; ++k) {
                vfloat4 wv = __builtin_nontemporal_load(&Wr[k * 64 + lane]);
                ah += dot4(wv, vv[k]);
                at += dot4(wv, tt[k]);
            }
            reduce2(ah, at);
            if (lane == 0) { red[w][r][0] = ah; red[w][r][1] = at; }
        }
        __syncthreads();
        if (tid < 32) {
            const int r = tid >> 1, s5 = tid & 1;
            float tot = red[0][r][s5] + red[1][r][s5] + red[2][r][s5] + red[3][r][s5];
            const int row = r0 + r;
            if (s5 == 0) xb[row]  = tot + wd_b2[row];   // identity layer, bias
            else         dxb[row] = tot;                 // tangent, no bias
        }
    }
}

extern "C" void kernel_launch(void* const* d_in, const int* in_sizes, int n_in,
                              void* d_out, int out_size, void* d_ws, size_t ws_size,
                              hipStream_t stream)
{
    const float* x     = (const float*)d_in[0];
    const float* dx    = (const float*)d_in[1];
    // d_in[2] = ddx: unused by the reference
    const float* we_w0 = (const float*)d_in[3];
    const float* we_b0 = (const float*)d_in[4];
    const float* we_w1 = (const float*)d_in[5];
    const float* we_b1 = (const float*)d_in[6];
    const float* we_w2 = (const float*)d_in[7];
    const float* we_b2 = (const float*)d_in[8];
    const float* wd_w0 = (const float*)d_in[9];
    const float* wd_b0 = (const float*)d_in[10];
    const float* wd_w1 = (const float*)d_in[11];
    const float* wd_b1 = (const float*)d_in[12];
    const float* wd_w2 = (const float*)d_in[13];
    const float* wd_b2 = (const float*)d_in[14];
    const float* E_w   = (const float*)d_in[15];
    const float* E_b   = (const float*)d_in[16];

    float* out = (float*)d_out;   // z[16] dz[16] dzb[16] xb[16384] dxb[16384]
    float* ws  = (float*)d_ws;

    // workspace layout (floats)
    float* h1    = ws;             // 4096
    float* t1    = ws + 4096;      // 4096
    float* h2    = ws + 8192;      // 1024
    float* t2    = ws + 9216;      // 1024
    float* g1    = ws + 10240;     // 1024
    float* s1    = ws + 11264;     // 1024
    float* g2    = ws + 12288;     // 4096
    float* s2    = ws + 16384;     // 4096
    float* part1 = ws + 20480;     // 4096 rows x 2 streams x 4 block-partials
    unsigned* bar = (unsigned*)(ws + 53248);   // barrier counter (64B-aligned)

    float* xb  = out + 48;
    float* dxb = out + 48 + 16384;

    // zero the grid-barrier counter (graph-capturable memset node)
    hipMemsetAsync(bar, 0, 64, stream);

    sindy_fused<<<dim3(NBLK), dim3(256), 0, stream>>>(
        x, dx, we_w0, we_b0, we_w1, we_b1, we_w2, we_b2,
        wd_w0, wd_b0, wd_w1, wd_b1, wd_w2, wd_b2, E_w, E_b,
        h1, t1, h2, t2, g1, s1, g2, s2, part1, bar, out, xb, dxb);
}

// Round 3
// 567.579 us; speedup vs baseline: 2.3913x; 2.3913x over previous
//
#include <hip/hip_runtime.h>
#include <math.h>

typedef float vfloat4 __attribute__((ext_vector_type(4)));

__device__ __forceinline__ float dot4(vfloat4 a, vfloat4 b) {
    return a.x * b.x + a.y * b.y + a.z * b.z + a.w * b.w;
}

// ---------------------------------------------------------------------------
// Block-per-row dual GEMV.
//   h_out[row] = f(dot(W[row], v) + b[row])
//   t_out[row] = f'(.) * dot(W[row], t)     (JVP tangent)
// One 256-thread block per row. The row is read as ONE contiguous coalesced
// stream (thread i gets float4 #i of each 4KB span), fully unrolled so the
// compiler keeps many dwordx4 loads in flight -> hides HBM latency without
// any cross-lane traffic in the inner loop. Exactly one wave-shuffle + LDS
// reduce per row at the end. W is single-use within an iteration -> nt loads.
// v/t are block-shared and stay hot in L1/L2.
// ---------------------------------------------------------------------------
template <int NCOLS, bool SIG>
__global__ __launch_bounds__(256, 2) void gemv_block(
    const float* __restrict__ W, const float* __restrict__ b,
    const float* __restrict__ v, const float* __restrict__ t,
    float* __restrict__ h_out, float* __restrict__ t_out)
{
    constexpr int F4PT = NCOLS / 4 / 256;   // float4s per thread (16,4,1)
    const int row = (int)blockIdx.x;
    const int tid = (int)threadIdx.x;
    const int lane = tid & 63;
    const int w = tid >> 6;

    const vfloat4* __restrict__ Wr = (const vfloat4*)(W + (size_t)row * NCOLS);
    const vfloat4* __restrict__ v4 = (const vfloat4*)v;
    const vfloat4* __restrict__ t4 = (const vfloat4*)t;

    float ah = 0.f, at = 0.f;
#pragma unroll
    for (int k = 0; k < F4PT; ++k) {
        const int i = tid + 256 * k;
        vfloat4 wv = __builtin_nontemporal_load(&Wr[i]);
        vfloat4 a = v4[i];
        vfloat4 c = t4[i];
        ah += dot4(wv, a);
        at += dot4(wv, c);
    }

    // one reduce per row: wave butterfly, then 4 wave-partials through LDS
#pragma unroll
    for (int off = 32; off; off >>= 1) {
        ah += __shfl_down(ah, off, 64);
        at += __shfl_down(at, off, 64);
    }
    __shared__ float red[4][2];
    if (lane == 0) { red[w][0] = ah; red[w][1] = at; }
    __syncthreads();
    if (tid == 0) {
        float A = red[0][0] + red[1][0] + red[2][0] + red[3][0] + b[row];
        float T = red[0][1] + red[1][1] + red[2][1] + red[3][1];
        if (SIG) {
            float s = 1.f / (1.f + expf(-A));
            h_out[row] = s;
            t_out[row] = s * (1.f - s) * T;
        } else {
            h_out[row] = A;
            t_out[row] = T;
        }
    }
}

// ---------------------------------------------------------------------------
// head kernel: single block, 1024 threads (16 waves).
//   z  = W2 @ h2 + b2      dz = W2 @ t2          (16 x 1024, wave per row)
//   theta = sindy_library(z)                      (984)
//   dzb = E_w @ theta + E_b                       (16 x 984, wave per row)
//   g1 = sigmoid(U0 @ z + c0), s1 = sig'*(U0 @ dzb)  (1024 rows, thread/row)
// ---------------------------------------------------------------------------
__global__ __launch_bounds__(1024) void head_kernel(
    const float* __restrict__ W2, const float* __restrict__ b2,
    const float* __restrict__ h2, const float* __restrict__ t2,
    const float* __restrict__ Ew, const float* __restrict__ Eb,
    const float* __restrict__ U0, const float* __restrict__ c0,
    float* __restrict__ out,
    float* __restrict__ g1, float* __restrict__ s1)
{
    __shared__ float z_s[16], dz_s[16], dzb_s[16];
    __shared__ __align__(16) float theta[984];

    const int tid = (int)threadIdx.x;
    const int lane = tid & 63;
    const int r = tid >> 6;            // wave id 0..15

    // ---- z, dz: wave r handles row r of W2 (1024 cols) ----
    {
        const vfloat4* Wr = (const vfloat4*)(W2 + r * 1024);
        const vfloat4* h4 = (const vfloat4*)h2;
        const vfloat4* t4 = (const vfloat4*)t2;
        float ah = 0.f, at = 0.f;
#pragma unroll
        for (int k = 0; k < 4; ++k) {
            const int i = lane + 64 * k;
            vfloat4 wv = Wr[i];
            ah += dot4(wv, h4[i]);
            at += dot4(wv, t4[i]);
        }
#pragma unroll
        for (int off = 32; off; off >>= 1) {
            ah += __shfl_down(ah, off, 64);
            at += __shfl_down(at, off, 64);
        }
        if (lane == 0) {
            z_s[r] = ah + b2[r];
            dz_s[r] = at;
        }
    }
    __syncthreads();

    // ---- sindy library: [1]*16 ++ z ++ quad(136) ++ cub(816) ----
    if (tid < 16) { theta[tid] = 1.0f; theta[16 + tid] = z_s[tid]; }
    for (int t5 = tid; t5 < 136; t5 += 1024) {
        int rem = t5, i = 0;
        while (rem >= 16 - i) { rem -= 16 - i; i++; }
        theta[32 + t5] = z_s[i] * z_s[i + rem];
    }
    for (int t5 = tid; t5 < 816; t5 += 1024) {
        int rem = t5, i = 0;
        for (;;) { int cnt = (16 - i) * (17 - i) >> 1; if (rem < cnt) break; rem -= cnt; i++; }
        int j = i;
        while (rem >= 16 - j) { rem -= 16 - j; j++; }
        theta[168 + t5] = z_s[i] * z_s[j] * z_s[j + rem];
    }
    __syncthreads();

    // ---- dzb = E_w @ theta + E_b: wave r handles row r (984 cols) ----
    {
        const vfloat4* Er = (const vfloat4*)(Ew + (size_t)r * 246);
        const vfloat4* th4 = (const vfloat4*)theta;
        float a = 0.f;
        for (int i = lane; i < 246; i += 64) {
            a += dot4(Er[i], th4[i]);
        }
#pragma unroll
        for (int off = 32; off; off >>= 1) a += __shfl_down(a, off, 64);
        if (lane == 0) dzb_s[r] = a + Eb[r];
    }
    __syncthreads();

    // ---- outputs z, dz, dzb ----
    if (tid < 16) {
        out[tid]      = z_s[tid];
        out[16 + tid] = dz_s[tid];
        out[32 + tid] = dzb_s[tid];
    }

    // ---- decoder layer 0: 1024 rows, one thread per row ----
    {
        const vfloat4* U4 = (const vfloat4*)(U0 + tid * 16);
        float ah = 0.f, at = 0.f;
#pragma unroll
        for (int q = 0; q < 4; ++q) {
            vfloat4 u = U4[q];
            ah += u.x * z_s[4*q] + u.y * z_s[4*q+1] + u.z * z_s[4*q+2] + u.w * z_s[4*q+3];
            at += u.x * dzb_s[4*q] + u.y * dzb_s[4*q+1] + u.z * dzb_s[4*q+2] + u.w * dzb_s[4*q+3];
        }
        ah += c0[tid];
        float s = 1.f / (1.f + expf(-ah));
        g1[tid] = s;
        s1[tid] = s * (1.f - s) * at;
    }
}

extern "C" void kernel_launch(void* const* d_in, const int* in_sizes, int n_in,
                              void* d_out, int out_size, void* d_ws, size_t ws_size,
                              hipStream_t stream)
{
    const float* x     = (const float*)d_in[0];
    const float* dx    = (const float*)d_in[1];
    // d_in[2] = ddx: unused by the reference
    const float* we_w0 = (const float*)d_in[3];
    const float* we_b0 = (const float*)d_in[4];
    const float* we_w1 = (const float*)d_in[5];
    const float* we_b1 = (const float*)d_in[6];
    const float* we_w2 = (const float*)d_in[7];
    const float* we_b2 = (const float*)d_in[8];
    const float* wd_w0 = (const float*)d_in[9];
    const float* wd_b0 = (const float*)d_in[10];
    const float* wd_w1 = (const float*)d_in[11];
    const float* wd_b1 = (const float*)d_in[12];
    const float* wd_w2 = (const float*)d_in[13];
    const float* wd_b2 = (const float*)d_in[14];
    const float* E_w   = (const float*)d_in[15];
    const float* E_b   = (const float*)d_in[16];

    float* out = (float*)d_out;   // z[16] dz[16] dzb[16] xb[16384] dxb[16384]
    float* ws  = (float*)d_ws;

    // workspace layout (floats)
    float* h1 = ws;            // 4096
    float* t1 = ws + 4096;     // 4096
    float* h2 = ws + 8192;     // 1024
    float* t2 = ws + 9216;     // 1024
    float* g1 = ws + 10240;    // 1024
    float* s1 = ws + 11264;    // 1024
    float* g2 = ws + 12288;    // 4096
    float* s2 = ws + 16384;    // 4096

    float* xb  = out + 48;
    float* dxb = out + 48 + 16384;

    // encoder layer 0: 4096 rows x 16384 cols, sigmoid (block per row)
    gemv_block<16384, true><<<4096, 256, 0, stream>>>(we_w0, we_b0, x, dx, h1, t1);
    // encoder layer 1: 1024 rows x 4096 cols, sigmoid
    gemv_block<4096, true><<<1024, 256, 0, stream>>>(we_w1, we_b1, h1, t1, h2, t2);
    // head: z/dz, sindy library, dzb, decoder layer 0
    head_kernel<<<1, 1024, 0, stream>>>(we_w2, we_b2, h2, t2, E_w, E_b,
                                        wd_w0, wd_b0, out, g1, s1);
    // decoder layer 1: 4096 rows x 1024 cols, sigmoid
    gemv_block<1024, true><<<4096, 256, 0, stream>>>(wd_w1, wd_b1, g1, s1, g2, s2);
    // decoder layer 2: 16384 rows x 4096 cols, identity -> xb, dxb
    gemv_block<4096, false><<<16384, 256, 0, stream>>>(wd_w2, wd_b2, g2, s2, xb, dxb);
}